// Round 12
// baseline (504.459 us; speedup 1.0000x reference)
//
#include <hip/hip_runtime.h>
#include <hip/hip_fp16.h>

#define B_ 256
#define T_ 512
#define H_ 128
#define M_ (B_ * T_)  // 131072 rows

typedef _Float16 f16x8 __attribute__((ext_vector_type(8)));
typedef float    f32x4 __attribute__((ext_vector_type(4)));

__device__ __forceinline__ float rcp_f(float a) { return __builtin_amdgcn_rcpf(a); }
__device__ __forceinline__ float sigmoid_f(float a) { return rcp_f(1.f + __expf(-a)); }
__device__ __forceinline__ float tanh_f(float a) { return 1.f - 2.f * rcp_f(__expf(2.f * a) + 1.f); }

// LDS-only barrier: global loads/stores stay in flight (T4: never vmcnt(0) per step).
__device__ __forceinline__ void lds_barrier() {
    asm volatile("s_waitcnt lgkmcnt(0)\n\ts_barrier" ::: "memory");
}

#define PINV(X) asm volatile("" : "+v"(X))

__device__ __forceinline__ __half cell_update(float g0, float g1, float g2, float g3, float& c) {
    float iv = sigmoid_f(g0), fv = sigmoid_f(g1);
    float gv = tanh_f(g2),   ov = sigmoid_f(g3);
    c = fv * c + iv * gv;
    return __float2half(ov * tanh_f(c));
}

// ---- device-visible (cross-XCD via L3) memory ops: sc0 sc1 ----
__device__ __forceinline__ void store_short_sc(uint64_t addr, unsigned v) {
    asm volatile("global_store_short %0, %1, off sc0 sc1" :: "v"(addr), "v"(v) : "memory");
}
__device__ __forceinline__ void store_flag_sc(uint64_t addr, unsigned v) {
    asm volatile("global_store_dword %0, %1, off sc0 sc1" :: "v"(addr), "v"(v) : "memory");
}
__device__ __forceinline__ unsigned load_flag_sc(uint64_t addr) {
    unsigned v;
    asm volatile("global_load_dword %0, %1, off sc0 sc1\n\ts_waitcnt vmcnt(0)"
                 : "=v"(v) : "v"(addr) : "memory");
    return v;
}
#define LOAD16_SC(dst, addr) \
    asm volatile("global_load_dwordx4 %0, %1, off sc0 sc1" : "=&v"(dst) : "v"(addr) : "memory")

// min over 8 per-wave flags
__device__ __forceinline__ void poll_min8(uint64_t base, unsigned target, int lane) {
    for (;;) {
        unsigned v = 0xFFFFFFFFu;
        if (lane < 8) v = load_flag_sc(base + (uint64_t)lane * 4);
        v = min(v, (unsigned)__shfl_xor((int)v, 1));
        v = min(v, (unsigned)__shfl_xor((int)v, 2));
        v = min(v, (unsigned)__shfl_xor((int)v, 4));
        unsigned seen = (unsigned)__shfl((int)v, 0);
        if (seen >= target) break;
        __builtin_amdgcn_s_sleep(8);
    }
}

#define MFMA16(A, BV, C) __builtin_amdgcn_mfma_f32_16x16x32_f16((A), (BV), (C), 0, 0, 0)
#define MF4(AV, WARR, KT) \
    ac0 = MFMA16(AV, WARR[0][KT], ac0); \
    ac1 = MFMA16(AV, WARR[1][KT], ac1); \
    ac2 = MFMA16(AV, WARR[2][KT], ac2); \
    ac3 = MFMA16(AV, WARR[3][KT], ac3);
#define PF4(AV, KT) \
    px0 = MFMA16(AV, wi[0][KT], px0); \
    px1 = MFMA16(AV, wi[1][KT], px1); \
    px2 = MFMA16(AV, wi[2][KT], px2); \
    px3 = MFMA16(AV, wi[3][KT], px3);

// ---------- one-time conversions ----------
__global__ __launch_bounds__(256)
void convert_kernel(const float* __restrict__ Wih0, const float* __restrict__ bih0, const float* __restrict__ bhh0,
                    const float* __restrict__ Whh0, const float* __restrict__ Wih1, const float* __restrict__ Whh1,
                    const float* __restrict__ bih1, const float* __restrict__ bhh1,
                    const float* __restrict__ Wl, const float* __restrict__ bl,
                    const float* __restrict__ Wo, const float* __restrict__ bo,
                    __half* __restrict__ W0b, __half* __restrict__ W1b,
                    __half* __restrict__ Whh0h, __half* __restrict__ Whh1h,
                    __half* __restrict__ Wc16, float* __restrict__ b0, float* __restrict__ b1,
                    float* __restrict__ bc)
{
    const int tid = threadIdx.x, bid = blockIdx.x;
    if (bid == 0) {
        for (int i = tid; i < 512; i += 256) { b0[i] = bih0[i] + bhh0[i]; b1[i] = bih1[i] + bhh1[i]; }
        for (int i = tid; i < 512 * 32; i += 256) {
            int r = i >> 5, k = i & 31;
            W0b[i] = __float2half(k < 30 ? Wih0[r * 30 + k] : 0.f);
        }
        for (int i = tid; i < 64 * 128; i += 256) {
            int j = i >> 7, k = i & 127;
            float a = 0.f;
            if (j < 63) for (int m = 0; m < 84; ++m) a += Wo[j * 84 + m] * Wl[m * 128 + k];
            Wc16[i] = __float2half(a);
        }
        if (tid < 64) {
            float a = 0.f;
            if (tid < 63) { a = bo[tid]; for (int m = 0; m < 84; ++m) a += Wo[tid * 84 + m] * bl[m]; }
            bc[tid] = a;
        }
    } else if (bid == 1) {
        for (int i = tid; i < 512 * 128; i += 256) W1b[i] = __float2half(Wih1[i]);
    } else if (bid == 2) {
        for (int i = tid; i < 512 * 128; i += 256) Whh0h[i] = __float2half(Whh0[i]);
    } else {
        for (int i = tid; i < 512 * 128; i += 256) Whh1h[i] = __float2half(Whh1[i]);
    }
}

// ---------- fused dual-layer recurrence, local burst-GEMM form ----------
// blocks [0,64):   layer-0: per-16-step burst xp0=Wih0@x+b0 -> LDS, rec, publish h1 (sc) + chunk flag
// blocks [64,128): layer-1: poll flag, load h1 chunk, burst xp1=Wih1@h1+b1 -> LDS, rec, write h2
// LDS 102KB > 80KB forces 1 block/CU -> 256-VGPR cap (R10/11: 76.8KB allowed 2 blocks -> 128 cap)
__global__ __launch_bounds__(512, 1)
void lstm_fused(const float* __restrict__ x,
                const __half* __restrict__ W0b, const __half* __restrict__ Whh0h,
                const __half* __restrict__ W1b, const __half* __restrict__ Whh1h,
                const float* __restrict__ b0, const float* __restrict__ b1,
                __half* __restrict__ h1g, __half* __restrict__ h2g,
                unsigned* __restrict__ flags)
{
    const int bid = blockIdx.x;
    const bool producer = bid < 64;
    const int g = bid & 63;           // batch group: batches 4g..4g+3
    const int tid = threadIdx.x;
    const int w = tid >> 6;           // wave -> units 16w..16w+15
    const int lane = tid & 63;
    const int l15 = lane & 15, qg = lane >> 4;
    const int j = w * 16 + l15;       // this lane's unit
    const int r = l15 >> 2;           // A-row batch (duplicated 4x -> LDS broadcast)

    __shared__ __align__(16) char hbuf_s[2][1280];   // h tile [4b][128u] f16, stride 320B
    __shared__ __align__(16) __half xl[4][129][32];  // producer x chunk (128 steps)
    __shared__ __align__(16) char xpch[64 * 1040 + 16];  // gate chunk: 64 rows (s*4+b) x 1040B
    char* const hb0 = hbuf_s[0];
    char* const hb1 = hbuf_s[1];

    const int ro0 = r * 320 + 0 * 64 + qg * 16;
    const int ro1 = r * 320 + 1 * 64 + qg * 16;
    const int ro2 = r * 320 + 2 * 64 + qg * 16;
    const int ro3 = r * 320 + 3 * 64 + qg * 16;
    const int wo  = qg * 320 + j * 2;
    const int xqoff = 8 * j;          // + row*1040

    for (int i = tid; i < 320; i += 512) ((unsigned*)hb0)[i] = 0;  // h(-1) = 0

    const uint64_t fb = (uint64_t)(uintptr_t)flags;
    const uint64_t flagbase = fb + (uint64_t)(g * 8) * 4;
    float c = 0.f;

// shared rec step: gates from LDS xpch, h tile double-buffered, one barrier
#define RSTEP(TT, HOUT) do {                                                    \
        const int t_ = (TT);                                                    \
        const char* rp_ = (t_ & 1) ? hb1 : hb0;                                 \
        char* wp_ = (t_ & 1) ? hb0 : hb1;                                       \
        uint2 xq = *(const uint2*)(xpch + ((t_ & 15) * 4 + qg) * 1040 + xqoff); \
        f16x8 a0_ = *(const f16x8*)(rp_ + ro0);                                 \
        f16x8 a1_ = *(const f16x8*)(rp_ + ro1);                                 \
        f16x8 a2_ = *(const f16x8*)(rp_ + ro2);                                 \
        f16x8 a3_ = *(const f16x8*)(rp_ + ro3);                                 \
        float2 flo = __half22float2(__builtin_bit_cast(__half2, xq.x));         \
        float2 fhi = __half22float2(__builtin_bit_cast(__half2, xq.y));         \
        f32x4 ac0 = (f32x4){flo.x, 0.f, 0.f, 0.f};                              \
        f32x4 ac1 = (f32x4){flo.y, 0.f, 0.f, 0.f};                              \
        f32x4 ac2 = (f32x4){fhi.x, 0.f, 0.f, 0.f};                              \
        f32x4 ac3 = (f32x4){fhi.y, 0.f, 0.f, 0.f};                              \
        MF4(a0_, wb, 0) MF4(a1_, wb, 1) MF4(a2_, wb, 2) MF4(a3_, wb, 3)         \
        __half hh_ = cell_update(ac0[0], ac1[0], ac2[0], ac3[0], c);            \
        *(__half*)(wp_ + wo) = hh_;                                             \
        HOUT;                                                                   \
        lds_barrier();                                                          \
    } while (0)

    if (producer) {
        float b0q[4];
        f16x8 wx[4], wb[4][4];
#pragma unroll
        for (int q = 0; q < 4; ++q) {
            b0q[q] = b0[q * 128 + j];
            wx[q] = *reinterpret_cast<const f16x8*>(W0b + (size_t)(q * 128 + j) * 32 + qg * 8);
            PINV(wx[q]);
#pragma unroll
            for (int kt = 0; kt < 4; ++kt) {
                wb[q][kt] = *reinterpret_cast<const f16x8*>(Whh0h + (size_t)(q * 128 + j) * 128 + kt * 32 + qg * 8);
                PINV(wb[q][kt]);
            }
        }
        // zero x padding cols once
        for (int idx = tid; idx < 1024; idx += 512) {
            int b4 = idx >> 8, rest = idx & 255;
            xl[b4][rest >> 1][30 + (rest & 1)] = __float2half(0.f);
        }
        const uint64_t pflag = flagbase + (uint64_t)w * 4;
        const uint64_t h1sb = (uint64_t)(uintptr_t)h1g + ((((uint64_t)(g * 4 + qg)) * T_) * H_ + j) * 2;
        __syncthreads();

        for (int xc = 0; xc < 4; ++xc) {
#pragma unroll 1
            for (int b4 = 0; b4 < 4; ++b4) {
                const float* src = x + ((size_t)(g * 4 + b4) * T_ + xc * 128) * 30;
                for (int idx = tid; idx < 3840; idx += 512) {
                    int tt = idx / 30, ii = idx - tt * 30;
                    xl[b4][tt][ii] = __float2half(src[idx]);
                }
            }
            __syncthreads();
#pragma unroll 1
            for (int sc = 0; sc < 8; ++sc) {
                const int cc = xc * 8 + sc;
                // ---- burst: xp0 chunk (64 rows = 16 steps x 4 batches), K=32 ----
#pragma unroll
                for (int rt = 0; rt < 4; ++rt) {
                    const int row = rt * 16 + l15;
                    const int s = row >> 2, b2 = row & 3;
                    f16x8 ax = *reinterpret_cast<const f16x8*>(&xl[b2][(cc * 16 + s) & 127][qg * 8]);
                    f32x4 px0 = (f32x4){b0q[0], b0q[0], b0q[0], b0q[0]};
                    f32x4 px1 = (f32x4){b0q[1], b0q[1], b0q[1], b0q[1]};
                    f32x4 px2 = (f32x4){b0q[2], b0q[2], b0q[2], b0q[2]};
                    f32x4 px3 = (f32x4){b0q[3], b0q[3], b0q[3], b0q[3]};
                    px0 = MFMA16(ax, wx[0], px0); px1 = MFMA16(ax, wx[1], px1);
                    px2 = MFMA16(ax, wx[2], px2); px3 = MFMA16(ax, wx[3], px3);
#pragma unroll
                    for (int r4 = 0; r4 < 4; ++r4) {
                        const int ro_ = rt * 16 + qg * 4 + r4;  // row = s*4+b
                        __half2 lo_ = __floats2half2_rn(px0[r4], px1[r4]);
                        __half2 hi_ = __floats2half2_rn(px2[r4], px3[r4]);
                        uint2 pk_;
                        pk_.x = __builtin_bit_cast(unsigned, lo_);
                        pk_.y = __builtin_bit_cast(unsigned, hi_);
                        *reinterpret_cast<uint2*>(xpch + ro_ * 1040 + 8 * j) = pk_;
                    }
                }
                lds_barrier();   // gate chunk visible
                const int tb = cc * 16;
                RSTEP(tb + 0,  store_short_sc(h1sb + (uint64_t)(tb + 0) * 256,  (unsigned)__builtin_bit_cast(unsigned short, hh_)));
                RSTEP(tb + 1,  store_short_sc(h1sb + (uint64_t)(tb + 1) * 256,  (unsigned)__builtin_bit_cast(unsigned short, hh_)));
                RSTEP(tb + 2,  store_short_sc(h1sb + (uint64_t)(tb + 2) * 256,  (unsigned)__builtin_bit_cast(unsigned short, hh_)));
                RSTEP(tb + 3,  store_short_sc(h1sb + (uint64_t)(tb + 3) * 256,  (unsigned)__builtin_bit_cast(unsigned short, hh_)));
                RSTEP(tb + 4,  store_short_sc(h1sb + (uint64_t)(tb + 4) * 256,  (unsigned)__builtin_bit_cast(unsigned short, hh_)));
                RSTEP(tb + 5,  store_short_sc(h1sb + (uint64_t)(tb + 5) * 256,  (unsigned)__builtin_bit_cast(unsigned short, hh_)));
                RSTEP(tb + 6,  store_short_sc(h1sb + (uint64_t)(tb + 6) * 256,  (unsigned)__builtin_bit_cast(unsigned short, hh_)));
                RSTEP(tb + 7,  store_short_sc(h1sb + (uint64_t)(tb + 7) * 256,  (unsigned)__builtin_bit_cast(unsigned short, hh_)));
                RSTEP(tb + 8,  store_short_sc(h1sb + (uint64_t)(tb + 8) * 256,  (unsigned)__builtin_bit_cast(unsigned short, hh_)));
                RSTEP(tb + 9,  store_short_sc(h1sb + (uint64_t)(tb + 9) * 256,  (unsigned)__builtin_bit_cast(unsigned short, hh_)));
                RSTEP(tb + 10, store_short_sc(h1sb + (uint64_t)(tb + 10) * 256, (unsigned)__builtin_bit_cast(unsigned short, hh_)));
                RSTEP(tb + 11, store_short_sc(h1sb + (uint64_t)(tb + 11) * 256, (unsigned)__builtin_bit_cast(unsigned short, hh_)));
                RSTEP(tb + 12, store_short_sc(h1sb + (uint64_t)(tb + 12) * 256, (unsigned)__builtin_bit_cast(unsigned short, hh_)));
                RSTEP(tb + 13, store_short_sc(h1sb + (uint64_t)(tb + 13) * 256, (unsigned)__builtin_bit_cast(unsigned short, hh_)));
                RSTEP(tb + 14, store_short_sc(h1sb + (uint64_t)(tb + 14) * 256, (unsigned)__builtin_bit_cast(unsigned short, hh_)));
                RSTEP(tb + 15, store_short_sc(h1sb + (uint64_t)(tb + 15) * 256, (unsigned)__builtin_bit_cast(unsigned short, hh_)));
                asm volatile("s_waitcnt vmcnt(0)" ::: "memory");   // once per 16 steps
                if (lane == 0) store_flag_sc(pflag, (unsigned)((cc + 1) * 16));
            }
        }
    } else {
        // ================= consumer: layer-1, local xp1 burst =================
        float b1q[4];
        f16x8 wb[4][4], wi[4][4];
#pragma unroll
        for (int q = 0; q < 4; ++q) {
            b1q[q] = b1[q * 128 + j];
#pragma unroll
            for (int kt = 0; kt < 4; ++kt) {
                wb[q][kt] = *reinterpret_cast<const f16x8*>(Whh1h + (size_t)(q * 128 + j) * 128 + kt * 32 + qg * 8);
                wi[q][kt] = *reinterpret_cast<const f16x8*>(W1b   + (size_t)(q * 128 + j) * 128 + kt * 32 + qg * 8);
                PINV(wb[q][kt]); PINV(wi[q][kt]);
            }
        }
        const uint64_t h1cb = (uint64_t)(uintptr_t)h1g + ((uint64_t)(g * 4) * T_ * H_) * 2;
        __half* h2p = h2g + ((size_t)(g * 4 + qg) * T_) * H_ + j;
        __syncthreads();

#pragma unroll 1
        for (int cc = 0; cc < 32; ++cc) {
            poll_min8(flagbase, (unsigned)((cc + 1) * 16), lane);
            // load h1 chunk A-fragments (sc): 16 x dwordx4 per lane
            uint4 fr0k0, fr0k1, fr0k2, fr0k3, fr1k0, fr1k1, fr1k2, fr1k3;
            uint4 fr2k0, fr2k1, fr2k2, fr2k3, fr3k0, fr3k1, fr3k2, fr3k3;
#define LDROW(RT, D0, D1, D2, D3) do {                                          \
            const int row_ = (RT) * 16 + l15;                                   \
            const int s_ = row_ >> 2, b2_ = row_ & 3;                           \
            uint64_t rb_ = h1cb + (((uint64_t)b2_ * T_ + cc * 16 + s_) * H_) * 2 + qg * 16; \
            LOAD16_SC(D0, rb_);        LOAD16_SC(D1, rb_ + 64);                 \
            LOAD16_SC(D2, rb_ + 128);  LOAD16_SC(D3, rb_ + 192);                \
        } while (0)
            LDROW(0, fr0k0, fr0k1, fr0k2, fr0k3);
            LDROW(1, fr1k0, fr1k1, fr1k2, fr1k3);
            LDROW(2, fr2k0, fr2k1, fr2k2, fr2k3);
            LDROW(3, fr3k0, fr3k1, fr3k2, fr3k3);
            asm volatile("s_waitcnt vmcnt(0)" ::: "memory");
            __builtin_amdgcn_sched_barrier(0);
#define GEMMROW(RT, D0, D1, D2, D3) do {                                        \
            f16x8 h0_ = __builtin_bit_cast(f16x8, D0);                          \
            f16x8 h1_ = __builtin_bit_cast(f16x8, D1);                          \
            f16x8 h2_ = __builtin_bit_cast(f16x8, D2);                          \
            f16x8 h3_ = __builtin_bit_cast(f16x8, D3);                          \
            f32x4 px0 = (f32x4){b1q[0], b1q[0], b1q[0], b1q[0]};                \
            f32x4 px1 = (f32x4){b1q[1], b1q[1], b1q[1], b1q[1]};                \
            f32x4 px2 = (f32x4){b1q[2], b1q[2], b1q[2], b1q[2]};                \
            f32x4 px3 = (f32x4){b1q[3], b1q[3], b1q[3], b1q[3]};                \
            PF4(h0_, 0) PF4(h1_, 1) PF4(h2_, 2) PF4(h3_, 3)                     \
            _Pragma("unroll")                                                   \
            for (int r4 = 0; r4 < 4; ++r4) {                                    \
                const int ro_ = (RT) * 16 + qg * 4 + r4;                        \
                __half2 lo_ = __floats2half2_rn(px0[r4], px1[r4]);              \
                __half2 hi_ = __floats2half2_rn(px2[r4], px3[r4]);              \
                uint2 pk_;                                                      \
                pk_.x = __builtin_bit_cast(unsigned, lo_);                      \
                pk_.y = __builtin_bit_cast(unsigned, hi_);                      \
                *reinterpret_cast<uint2*>(xpch + ro_ * 1040 + 8 * j) = pk_;     \
            }                                                                   \
        } while (0)
            GEMMROW(0, fr0k0, fr0k1, fr0k2, fr0k3);
            GEMMROW(1, fr1k0, fr1k1, fr1k2, fr1k3);
            GEMMROW(2, fr2k0, fr2k1, fr2k2, fr2k3);
            GEMMROW(3, fr3k0, fr3k1, fr3k2, fr3k3);
            lds_barrier();   // gate chunk visible
            const int tb = cc * 16;
            RSTEP(tb + 0,  h2p[(size_t)(tb + 0) * H_] = hh_);
            RSTEP(tb + 1,  h2p[(size_t)(tb + 1) * H_] = hh_);
            RSTEP(tb + 2,  h2p[(size_t)(tb + 2) * H_] = hh_);
            RSTEP(tb + 3,  h2p[(size_t)(tb + 3) * H_] = hh_);
            RSTEP(tb + 4,  h2p[(size_t)(tb + 4) * H_] = hh_);
            RSTEP(tb + 5,  h2p[(size_t)(tb + 5) * H_] = hh_);
            RSTEP(tb + 6,  h2p[(size_t)(tb + 6) * H_] = hh_);
            RSTEP(tb + 7,  h2p[(size_t)(tb + 7) * H_] = hh_);
            RSTEP(tb + 8,  h2p[(size_t)(tb + 8) * H_] = hh_);
            RSTEP(tb + 9,  h2p[(size_t)(tb + 9) * H_] = hh_);
            RSTEP(tb + 10, h2p[(size_t)(tb + 10) * H_] = hh_);
            RSTEP(tb + 11, h2p[(size_t)(tb + 11) * H_] = hh_);
            RSTEP(tb + 12, h2p[(size_t)(tb + 12) * H_] = hh_);
            RSTEP(tb + 13, h2p[(size_t)(tb + 13) * H_] = hh_);
            RSTEP(tb + 14, h2p[(size_t)(tb + 14) * H_] = hh_);
            RSTEP(tb + 15, h2p[(size_t)(tb + 15) * H_] = hh_);
        }
    }
}

// ---------- head: out = h2 @ Wc^T + bc (63 cols, f32) ----------
__global__ __launch_bounds__(256, 4)
void head_kernel(const __half* __restrict__ in, const __half* __restrict__ W16,
                 const float* __restrict__ bias, float* __restrict__ outp)
{
    constexpr int KK = 128;
    const int lane = threadIdx.x & 63;
    const int wn = threadIdx.x >> 6;
    const int rowbase = blockIdx.x * 64;  // ROWT=4
    const int colbase = wn * 16;
    const int l15 = lane & 15, lk = (lane >> 4) * 8;

    float bcol = bias[colbase + l15];
    f32x4 acc[4];
#pragma unroll
    for (int rt = 0; rt < 4; ++rt) acc[rt] = (f32x4){0.f, 0.f, 0.f, 0.f};

#pragma unroll
    for (int kt = 0; kt < 4; ++kt) {
        f16x8 bv = *reinterpret_cast<const f16x8*>(W16 + (size_t)(colbase + l15) * KK + kt * 32 + lk);
#pragma unroll
        for (int rt = 0; rt < 4; ++rt) {
            f16x8 a = *reinterpret_cast<const f16x8*>(in + (size_t)(rowbase + rt * 16 + l15) * KK + kt * 32 + lk);
            acc[rt] = __builtin_amdgcn_mfma_f32_16x16x32_f16(a, bv, acc[rt], 0, 0, 0);
        }
    }
    const int col = colbase + l15;
#pragma unroll
    for (int rt = 0; rt < 4; ++rt)
#pragma unroll
        for (int rr = 0; rr < 4; ++rr) {
            const int row = rowbase + rt * 16 + (lane >> 4) * 4 + rr;
            if (col < 63) outp[(size_t)row * 63 + col] = acc[rt][rr] + bcol;
        }
}

extern "C" void kernel_launch(void* const* d_in, const int* in_sizes, int n_in,
                              void* d_out, int out_size, void* d_ws, size_t ws_size,
                              hipStream_t stream)
{
    const float* x    = (const float*)d_in[0];
    const float* Wih0 = (const float*)d_in[1];
    const float* Whh0 = (const float*)d_in[2];
    const float* bih0 = (const float*)d_in[3];
    const float* bhh0 = (const float*)d_in[4];
    const float* Wih1 = (const float*)d_in[5];
    const float* Whh1 = (const float*)d_in[6];
    const float* bih1 = (const float*)d_in[7];
    const float* bhh1 = (const float*)d_in[8];
    const float* Wl   = (const float*)d_in[9];
    const float* bl   = (const float*)d_in[10];
    const float* Wo   = (const float*)d_in[11];
    const float* bo   = (const float*)d_in[12];
    float* out = (float*)d_out;

    char* ws = (char*)d_ws;
    size_t off = 0;
    auto carve = [&](size_t bytes) { void* p = ws + off; off += (bytes + 255) & ~(size_t)255; return p; };
    __half* h1    = (__half*)carve((size_t)M_ * 128 * 2);   // 33.5 MB (full-size, no ring reuse)
    __half* h2    = (__half*)carve((size_t)M_ * 128 * 2);   // 33.5 MB
    __half* W0b   = (__half*)carve(512 * 32 * 2);
    __half* W1b   = (__half*)carve(512 * 128 * 2);
    __half* Whh0h = (__half*)carve(512 * 128 * 2);
    __half* Whh1h = (__half*)carve(512 * 128 * 2);
    __half* Wc16  = (__half*)carve(64 * 128 * 2);
    float*  b0    = (float*)carve(512 * 4);
    float*  b1    = (float*)carve(512 * 4);
    float*  bc    = (float*)carve(64 * 4);
    unsigned* flags = (unsigned*)carve(2048 * 4);

    hipLaunchKernelGGL(convert_kernel, dim3(4), dim3(256), 0, stream,
                       Wih0, bih0, bhh0, Whh0, Wih1, Whh1, bih1, bhh1, Wl, bl, Wo, bo,
                       W0b, W1b, Whh0h, Whh1h, Wc16, b0, b1, bc);

    hipMemsetAsync(flags, 0, 2048 * 4, stream);  // flags must start at 0 every replay

    hipLaunchKernelGGL(lstm_fused, dim3(128), dim3(512), 0, stream,
                       x, W0b, Whh0h, W1b, Whh1h, b0, b1, h1, h2, flags);

    hipLaunchKernelGGL(head_kernel, dim3(M_ / 64), dim3(256), 0, stream,
                       h2, Wc16, bc, out);
}

// Round 13
// 444.026 us; speedup vs baseline: 1.1361x; 1.1361x over previous
//
#include <hip/hip_runtime.h>
#include <hip/hip_fp16.h>

#define B_ 256
#define T_ 512
#define H_ 128
#define M_ (B_ * T_)  // 131072 rows

typedef _Float16 f16x8 __attribute__((ext_vector_type(8)));
typedef float    f32x4 __attribute__((ext_vector_type(4)));

__device__ __forceinline__ float rcp_f(float a) { return __builtin_amdgcn_rcpf(a); }
__device__ __forceinline__ float sigmoid_f(float a) { return rcp_f(1.f + __expf(-a)); }
__device__ __forceinline__ float tanh_f(float a) { return 1.f - 2.f * rcp_f(__expf(2.f * a) + 1.f); }

__device__ __forceinline__ void lds_barrier() {
    asm volatile("s_waitcnt lgkmcnt(0)\n\ts_barrier" ::: "memory");
}

#define PINV(X) asm volatile("" : "+v"(X))

__device__ __forceinline__ __half cell_update(float g0, float g1, float g2, float g3, float& c) {
    float iv = sigmoid_f(g0), fv = sigmoid_f(g1);
    float gv = tanh_f(g2),   ov = sigmoid_f(g3);
    c = fv * c + iv * gv;
    return __float2half(ov * tanh_f(c));
}

// ---- device-visible (cross-XCD via L3) ops: sc0 sc1 ----
__device__ __forceinline__ void store_dwordx2_sc(uint64_t addr, uint2 v) {
    asm volatile("global_store_dwordx2 %0, %1, off sc0 sc1" :: "v"(addr), "v"(v) : "memory");
}
__device__ __forceinline__ void store_flag_sc(uint64_t addr, unsigned v) {
    asm volatile("global_store_dword %0, %1, off sc0 sc1" :: "v"(addr), "v"(v) : "memory");
}
__device__ __forceinline__ unsigned load_flag_sc(uint64_t addr) {
    unsigned v;
    asm volatile("global_load_dword %0, %1, off sc0 sc1\n\ts_waitcnt vmcnt(0)"
                 : "=v"(v) : "v"(addr) : "memory");
    return v;
}
#define LOAD8_SC(dst, addr) \
    asm volatile("global_load_dwordx2 %0, %1, off sc0 sc1" : "=&v"(dst) : "v"(addr) : "memory")

__device__ __forceinline__ void poll_one(uint64_t addr, unsigned target) {
    for (;;) {
        unsigned v = load_flag_sc(addr);
        if (v >= target) break;
        __builtin_amdgcn_s_sleep(8);
    }
}

#define MFMA16(A, BV, C) __builtin_amdgcn_mfma_f32_16x16x32_f16((A), (BV), (C), 0, 0, 0)
#define MF4(AV, WARR, KT) \
    ac0 = MFMA16(AV, WARR[0][KT], ac0); \
    ac1 = MFMA16(AV, WARR[1][KT], ac1); \
    ac2 = MFMA16(AV, WARR[2][KT], ac2); \
    ac3 = MFMA16(AV, WARR[3][KT], ac3);

// ---------- one-time conversions ----------
__global__ __launch_bounds__(256)
void convert_kernel(const float* __restrict__ Wih0, const float* __restrict__ bih0, const float* __restrict__ bhh0,
                    const float* __restrict__ Whh0, const float* __restrict__ Wih1, const float* __restrict__ Whh1,
                    const float* __restrict__ bih1, const float* __restrict__ bhh1,
                    const float* __restrict__ Wl, const float* __restrict__ bl,
                    const float* __restrict__ Wo, const float* __restrict__ bo,
                    __half* __restrict__ W0b, __half* __restrict__ W1b,
                    __half* __restrict__ Whh0h, __half* __restrict__ Whh1h,
                    __half* __restrict__ Wc16, float* __restrict__ b0, float* __restrict__ b1,
                    float* __restrict__ bc)
{
    const int tid = threadIdx.x, bid = blockIdx.x;
    if (bid == 0) {
        for (int i = tid; i < 512; i += 256) { b0[i] = bih0[i] + bhh0[i]; b1[i] = bih1[i] + bhh1[i]; }
        for (int i = tid; i < 512 * 32; i += 256) {
            int r = i >> 5, k = i & 31;
            W0b[i] = __float2half(k < 30 ? Wih0[r * 30 + k] : 0.f);
        }
        for (int i = tid; i < 64 * 128; i += 256) {
            int j = i >> 7, k = i & 127;
            float a = 0.f;
            if (j < 63) for (int m = 0; m < 84; ++m) a += Wo[j * 84 + m] * Wl[m * 128 + k];
            Wc16[i] = __float2half(a);
        }
        if (tid < 64) {
            float a = 0.f;
            if (tid < 63) { a = bo[tid]; for (int m = 0; m < 84; ++m) a += Wo[tid * 84 + m] * bl[m]; }
            bc[tid] = a;
        }
    } else if (bid == 1) {
        for (int i = tid; i < 512 * 128; i += 256) W1b[i] = __float2half(Wih1[i]);
    } else if (bid == 2) {
        for (int i = tid; i < 512 * 128; i += 256) Whh0h[i] = __float2half(Whh0[i]);
    } else {
        for (int i = tid; i < 512 * 128; i += 256) Whh1h[i] = __float2half(Whh1[i]);
    }
}

// ---------- fused dual-layer recurrence, wave-specialized ----------
// blocks [0,64)  producer: waves 0-3 layer-0 rec (32 units each, Whh0+Wih0);
//                          waves 4-7 xp1=Wih1@h1 GEMM from LDS h1-ring -> global (sc) + flags
// blocks [64,128) consumer: waves 0-3 layer-1 rec (Whh1); waves 4-7 xp1 global -> LDS gate buffer
__global__ __launch_bounds__(512, 1)
void lstm_fused(const float* __restrict__ x,
                const __half* __restrict__ W0b, const __half* __restrict__ Whh0h,
                const __half* __restrict__ W1b, const __half* __restrict__ Whh1h,
                const float* __restrict__ b0, const float* __restrict__ b1,
                __half* __restrict__ xp, __half* __restrict__ h2g,
                unsigned* __restrict__ flags)
{
    const int bid = blockIdx.x;
    const bool producer = bid < 64;
    const int g = bid & 63;
    const int tid = threadIdx.x;
    const int w = tid >> 6;
    const int lane = tid & 63;
    const int l15 = lane & 15, qg = lane >> 4;
    const int r = l15 >> 2;

    __shared__ __align__(16) char hist[32 * 1280];    // producer h1 ring [32 steps][4b x 320B]
    __shared__ __align__(16) char hbuf_s[2][1280];    // consumer h2 tile
    __shared__ __align__(16) __half xl[4][129][32];   // producer x chunk
    __shared__ __align__(16) char gb[2 * 32 * 1040];  // consumer gate buffer: 2 x 32 rows x 1040B
    char* const hb0 = hbuf_s[0];
    char* const hb1 = hbuf_s[1];

    const int ro0 = r * 320 + 0 * 64 + qg * 16;
    const int ro1 = r * 320 + 1 * 64 + qg * 16;
    const int ro2 = r * 320 + 2 * 64 + qg * 16;
    const int ro3 = r * 320 + 3 * 64 + qg * 16;

    const uint64_t fb = (uint64_t)(uintptr_t)flags;
    const uint64_t xpb = (uint64_t)(uintptr_t)xp;

    if (producer) {
        for (int i = tid; i < 10240; i += 512) ((unsigned*)hist)[i] = 0;  // h1(-1)=0
        // zero x padding cols
        for (int idx = tid; idx < 1024; idx += 512) {
            int b4 = idx >> 8, rest = idx & 255;
            xl[b4][rest >> 1][30 + (rest & 1)] = __float2half(0.f);
        }

        if (w < 4) {
            // ---- rec wave: tiles 2w, 2w+1 ----
            const int j0 = (2 * w) * 16 + l15, j1 = (2 * w + 1) * 16 + l15;
            float bq0[4], bq1[4];
            f16x8 wx0[4], wx1[4], wb0[4][4], wb1[4][4];
#pragma unroll
            for (int q = 0; q < 4; ++q) {
                bq0[q] = b0[q * 128 + j0]; bq1[q] = b0[q * 128 + j1];
                wx0[q] = *reinterpret_cast<const f16x8*>(W0b + (size_t)(q * 128 + j0) * 32 + qg * 8);
                wx1[q] = *reinterpret_cast<const f16x8*>(W0b + (size_t)(q * 128 + j1) * 32 + qg * 8);
                PINV(wx0[q]); PINV(wx1[q]);
#pragma unroll
                for (int kt = 0; kt < 4; ++kt) {
                    wb0[q][kt] = *reinterpret_cast<const f16x8*>(Whh0h + (size_t)(q * 128 + j0) * 128 + kt * 32 + qg * 8);
                    wb1[q][kt] = *reinterpret_cast<const f16x8*>(Whh0h + (size_t)(q * 128 + j1) * 128 + kt * 32 + qg * 8);
                    PINV(wb0[q][kt]); PINV(wb1[q][kt]);
                }
            }
            const char* xlb = (const char*)xl;
            const int xro = r * 8256 + qg * 16;
            float c0 = 0.f, c1 = 0.f;
            __syncthreads();

#define PRSTEP(TT) do {                                                         \
            const int t_ = (TT);                                                \
            const char* rp_ = hist + (((t_ + 31) & 31) * 1280);                 \
            char* wp_ = hist + ((t_ & 31) * 1280);                              \
            f16x8 a0_ = *(const f16x8*)(rp_ + ro0);                             \
            f16x8 a1_ = *(const f16x8*)(rp_ + ro1);                             \
            f16x8 a2_ = *(const f16x8*)(rp_ + ro2);                             \
            f16x8 a3_ = *(const f16x8*)(rp_ + ro3);                             \
            f16x8 ax_ = *(const f16x8*)(xlb + xro + (t_ & 127) * 64);           \
            {   f32x4 ac0 = (f32x4){bq0[0], 0.f, 0.f, 0.f};                     \
                f32x4 ac1 = (f32x4){bq0[1], 0.f, 0.f, 0.f};                     \
                f32x4 ac2 = (f32x4){bq0[2], 0.f, 0.f, 0.f};                     \
                f32x4 ac3 = (f32x4){bq0[3], 0.f, 0.f, 0.f};                     \
                ac0 = MFMA16(ax_, wx0[0], ac0); ac1 = MFMA16(ax_, wx0[1], ac1); \
                ac2 = MFMA16(ax_, wx0[2], ac2); ac3 = MFMA16(ax_, wx0[3], ac3); \
                MF4(a0_, wb0, 0) MF4(a1_, wb0, 1) MF4(a2_, wb0, 2) MF4(a3_, wb0, 3) \
                __half hh_ = cell_update(ac0[0], ac1[0], ac2[0], ac3[0], c0);   \
                *(__half*)(wp_ + qg * 320 + j0 * 2) = hh_; }                    \
            {   f32x4 ac0 = (f32x4){bq1[0], 0.f, 0.f, 0.f};                     \
                f32x4 ac1 = (f32x4){bq1[1], 0.f, 0.f, 0.f};                     \
                f32x4 ac2 = (f32x4){bq1[2], 0.f, 0.f, 0.f};                     \
                f32x4 ac3 = (f32x4){bq1[3], 0.f, 0.f, 0.f};                     \
                ac0 = MFMA16(ax_, wx1[0], ac0); ac1 = MFMA16(ax_, wx1[1], ac1); \
                ac2 = MFMA16(ax_, wx1[2], ac2); ac3 = MFMA16(ax_, wx1[3], ac3); \
                MF4(a0_, wb1, 0) MF4(a1_, wb1, 1) MF4(a2_, wb1, 2) MF4(a3_, wb1, 3) \
                __half hh_ = cell_update(ac0[0], ac1[0], ac2[0], ac3[0], c1);   \
                *(__half*)(wp_ + qg * 320 + j1 * 2) = hh_; }                    \
            lds_barrier();                                                      \
        } while (0)

            for (int xc = 0; xc < 4; ++xc) {
#pragma unroll 1
                for (int b4 = 0; b4 < 4; ++b4) {
                    const float* src = x + ((size_t)(g * 4 + b4) * T_ + xc * 128) * 30;
                    for (int idx = tid; idx < 3840; idx += 512) {
                        int tt = idx / 30, ii = idx - tt * 30;
                        xl[b4][tt][ii] = __float2half(src[idx]);
                    }
                }
                __syncthreads();
#pragma unroll 1
                for (int ts = 0; ts < 128; ts += 2) {
                    PRSTEP(xc * 128 + ts);
                    PRSTEP(xc * 128 + ts + 1);
                }
            }
        } else {
            // ---- proj wave p: xp1 GEMM quarters for tiles 2p, 2p+1, spread over steps ----
            const int p = w - 4;
            float b14[4];
            f16x8 wi0[4][4], wi1[4][4];
            const int pj0 = (2 * p) * 16 + l15, pj1 = (2 * p + 1) * 16 + l15;
#pragma unroll
            for (int q = 0; q < 4; ++q) {
                b14[q] = b1[q * 128 + (p * 32 + (q & 0))];  // placeholder, fixed below
            }
            // biases are per output unit; each quarter uses its own tile's bias vector rows.
            float b14a[4], b14b[4];
#pragma unroll
            for (int q = 0; q < 4; ++q) {
                b14a[q] = b1[q * 128 + pj0];
                b14b[q] = b1[q * 128 + pj1];
#pragma unroll
                for (int kt = 0; kt < 4; ++kt) {
                    wi0[q][kt] = *reinterpret_cast<const f16x8*>(W1b + (size_t)(q * 128 + pj0) * 128 + kt * 32 + qg * 8);
                    wi1[q][kt] = *reinterpret_cast<const f16x8*>(W1b + (size_t)(q * 128 + pj1) * 128 + kt * 32 + qg * 8);
                    PINV(wi0[q][kt]); PINV(wi1[q][kt]);
                }
            }
            (void)b14;
            const uint64_t pfl = fb + (uint64_t)(g * 4 + p) * 4;
            __syncthreads();

#define QUARTER(WI, BV, JT, RT) do {                                            \
            const int si_ = (RT) * 4 + (l15 >> 2), bb_ = l15 & 3;               \
            const char* ap_ = hist + (((cc_ * 8 + si_) & 31) * 1280) + bb_ * 320 + qg * 16; \
            f16x8 h0_ = *(const f16x8*)(ap_);                                   \
            f16x8 h1_ = *(const f16x8*)(ap_ + 64);                              \
            f16x8 h2_ = *(const f16x8*)(ap_ + 128);                             \
            f16x8 h3_ = *(const f16x8*)(ap_ + 192);                             \
            f32x4 px0 = (f32x4){BV[0], BV[0], BV[0], BV[0]};                    \
            f32x4 px1 = (f32x4){BV[1], BV[1], BV[1], BV[1]};                    \
            f32x4 px2 = (f32x4){BV[2], BV[2], BV[2], BV[2]};                    \
            f32x4 px3 = (f32x4){BV[3], BV[3], BV[3], BV[3]};                    \
            px0 = MFMA16(h0_, WI[0][0], px0); px1 = MFMA16(h0_, WI[1][0], px1); \
            px2 = MFMA16(h0_, WI[2][0], px2); px3 = MFMA16(h0_, WI[3][0], px3); \
            px0 = MFMA16(h1_, WI[0][1], px0); px1 = MFMA16(h1_, WI[1][1], px1); \
            px2 = MFMA16(h1_, WI[2][1], px2); px3 = MFMA16(h1_, WI[3][1], px3); \
            px0 = MFMA16(h2_, WI[0][2], px0); px1 = MFMA16(h2_, WI[1][2], px1); \
            px2 = MFMA16(h2_, WI[2][2], px2); px3 = MFMA16(h2_, WI[3][2], px3); \
            px0 = MFMA16(h3_, WI[0][3], px0); px1 = MFMA16(h3_, WI[1][3], px1); \
            px2 = MFMA16(h3_, WI[2][3], px2); px3 = MFMA16(h3_, WI[3][3], px3); \
            _Pragma("unroll")                                                   \
            for (int r4 = 0; r4 < 4; ++r4) {                                    \
                uint64_t ad_ = xpb + ((uint64_t)((g * 4 + r4) * T_ + cc_ * 8 + (RT) * 4 + qg) << 10) + 8 * (JT); \
                __half2 lo_ = __floats2half2_rn(px0[r4], px1[r4]);              \
                __half2 hi_ = __floats2half2_rn(px2[r4], px3[r4]);              \
                uint2 pk_;                                                      \
                pk_.x = __builtin_bit_cast(unsigned, lo_);                      \
                pk_.y = __builtin_bit_cast(unsigned, hi_);                      \
                store_dwordx2_sc(ad_, pk_);                                     \
            }                                                                   \
        } while (0)

            for (int xc = 0; xc < 4; ++xc) {
#pragma unroll 1
                for (int b4 = 0; b4 < 4; ++b4) {
                    const float* src = x + ((size_t)(g * 4 + b4) * T_ + xc * 128) * 30;
                    for (int idx = tid; idx < 3840; idx += 512) {
                        int tt = idx / 30, ii = idx - tt * 30;
                        xl[b4][tt][ii] = __float2half(src[idx]);
                    }
                }
                __syncthreads();
#pragma unroll 1
                for (int ts = 0; ts < 128; ts += 2) {
                    const int t0_ = xc * 128 + ts;
                    {   // even step
                        const int ph = t0_ & 7;
                        const int cc_ = (t0_ >> 3) - 1;
                        if (t0_ >= 8) {
                            if (ph == 0)      QUARTER(wi0, b14a, pj0, 0);
                            else if (ph == 2) QUARTER(wi1, b14b, pj1, 0);
                            else if (ph == 4) {
                                asm volatile("s_waitcnt vmcnt(0)" ::: "memory");
                                if (lane == 0) store_flag_sc(pfl, (unsigned)((t0_ >> 3) * 8));
                            }
                        }
                        lds_barrier();
                    }
                    {   // odd step
                        const int t1_ = t0_ + 1;
                        const int ph = t1_ & 7;
                        const int cc_ = (t1_ >> 3) - 1;
                        if (t1_ >= 8) {
                            if (ph == 1)      QUARTER(wi0, b14a, pj0, 1);
                            else if (ph == 3) QUARTER(wi1, b14b, pj1, 1);
                        }
                        lds_barrier();
                    }
                }
            }
            // epilogue: chunk 63
            {
                const int cc_ = 63;
                QUARTER(wi0, b14a, pj0, 0);
                QUARTER(wi0, b14a, pj0, 1);
                QUARTER(wi1, b14b, pj1, 0);
                QUARTER(wi1, b14b, pj1, 1);
                asm volatile("s_waitcnt vmcnt(0)" ::: "memory");
                if (lane == 0) store_flag_sc(pfl, 512u);
            }
        }
    } else {
        // ================= consumer =================
        for (int i = tid; i < 320; i += 512) ((unsigned*)hb0)[i] = 0;  // h2(-1)=0
        if (w < 4) {
            const int j0 = (2 * w) * 16 + l15, j1 = (2 * w + 1) * 16 + l15;
            f16x8 wb0[4][4], wb1[4][4];
#pragma unroll
            for (int q = 0; q < 4; ++q)
#pragma unroll
                for (int kt = 0; kt < 4; ++kt) {
                    wb0[q][kt] = *reinterpret_cast<const f16x8*>(Whh1h + (size_t)(q * 128 + j0) * 128 + kt * 32 + qg * 8);
                    wb1[q][kt] = *reinterpret_cast<const f16x8*>(Whh1h + (size_t)(q * 128 + j1) * 128 + kt * 32 + qg * 8);
                    PINV(wb0[q][kt]); PINV(wb1[q][kt]);
                }
            __half* h2p0 = h2g + ((size_t)(g * 4 + qg) * T_) * H_ + j0;
            __half* h2p1 = h2g + ((size_t)(g * 4 + qg) * T_) * H_ + j1;
            float c0 = 0.f, c1 = 0.f;
            __syncthreads();   // pairs with proj prologue
            __syncthreads();

#define CRSTEP(TT, RP, WP) do {                                                 \
            const int t_ = (TT);                                                \
            const char* gq_ = gb + (((t_ >> 3) & 1) * 33280) + ((t_ & 7) * 4 + qg) * 1040; \
            uint2 x0_ = *(const uint2*)(gq_ + 8 * j0);                          \
            uint2 x1_ = *(const uint2*)(gq_ + 8 * j1);                          \
            f16x8 a0_ = *(const f16x8*)((RP) + ro0);                            \
            f16x8 a1_ = *(const f16x8*)((RP) + ro1);                            \
            f16x8 a2_ = *(const f16x8*)((RP) + ro2);                            \
            f16x8 a3_ = *(const f16x8*)((RP) + ro3);                            \
            {   float2 flo = __half22float2(__builtin_bit_cast(__half2, x0_.x)); \
                float2 fhi = __half22float2(__builtin_bit_cast(__half2, x0_.y)); \
                f32x4 ac0 = (f32x4){flo.x, 0.f, 0.f, 0.f};                      \
                f32x4 ac1 = (f32x4){flo.y, 0.f, 0.f, 0.f};                      \
                f32x4 ac2 = (f32x4){fhi.x, 0.f, 0.f, 0.f};                      \
                f32x4 ac3 = (f32x4){fhi.y, 0.f, 0.f, 0.f};                      \
                MF4(a0_, wb0, 0) MF4(a1_, wb0, 1) MF4(a2_, wb0, 2) MF4(a3_, wb0, 3) \
                __half hh_ = cell_update(ac0[0], ac1[0], ac2[0], ac3[0], c0);   \
                *(__half*)((WP) + qg * 320 + j0 * 2) = hh_;                     \
                h2p0[(size_t)t_ * H_] = hh_; }                                  \
            {   float2 flo = __half22float2(__builtin_bit_cast(__half2, x1_.x)); \
                float2 fhi = __half22float2(__builtin_bit_cast(__half2, x1_.y)); \
                f32x4 ac0 = (f32x4){flo.x, 0.f, 0.f, 0.f};                      \
                f32x4 ac1 = (f32x4){flo.y, 0.f, 0.f, 0.f};                      \
                f32x4 ac2 = (f32x4){fhi.x, 0.f, 0.f, 0.f};                      \
                f32x4 ac3 = (f32x4){fhi.y, 0.f, 0.f, 0.f};                      \
                MF4(a0_, wb1, 0) MF4(a1_, wb1, 1) MF4(a2_, wb1, 2) MF4(a3_, wb1, 3) \
                __half hh_ = cell_update(ac0[0], ac1[0], ac2[0], ac3[0], c1);   \
                *(__half*)((WP) + qg * 320 + j1 * 2) = hh_;                     \
                h2p1[(size_t)t_ * H_] = hh_; }                                  \
            lds_barrier();                                                      \
        } while (0)

#pragma unroll 1
            for (int t = 0; t < T_; t += 2) {
                CRSTEP(t, hb0, hb1);
                CRSTEP(t + 1, hb1, hb0);
            }
        } else {
            // ---- proj wave p: stage xp1 chunks into gate buffer, 1 chunk ahead ----
            const int p = w - 4;
            const int pj0 = (2 * p) * 16 + l15, pj1 = (2 * p + 1) * 16 + l15;
            const uint64_t pfl = fb + (uint64_t)(g * 4 + p) * 4;
            const uint64_t xrow = xpb + ((uint64_t)((g * 4 + qg) * T_) << 10);
            uint2 qA0, qA1, qA2, qA3, qA4, qA5, qA6, qA7;
            uint2 qB0, qB1, qB2, qB3, qB4, qB5, qB6, qB7;
            __syncthreads();
            // prologue: load chunk 0 into gb[0]
            poll_one(pfl, 8u);
            LOAD8_SC(qA0, xrow + ((uint64_t)0 << 10) + 8 * pj0); LOAD8_SC(qA1, xrow + ((uint64_t)1 << 10) + 8 * pj0);
            LOAD8_SC(qA2, xrow + ((uint64_t)2 << 10) + 8 * pj0); LOAD8_SC(qA3, xrow + ((uint64_t)3 << 10) + 8 * pj0);
            LOAD8_SC(qA4, xrow + ((uint64_t)4 << 10) + 8 * pj0); LOAD8_SC(qA5, xrow + ((uint64_t)5 << 10) + 8 * pj0);
            LOAD8_SC(qA6, xrow + ((uint64_t)6 << 10) + 8 * pj0); LOAD8_SC(qA7, xrow + ((uint64_t)7 << 10) + 8 * pj0);
            LOAD8_SC(qB0, xrow + ((uint64_t)0 << 10) + 8 * pj1); LOAD8_SC(qB1, xrow + ((uint64_t)1 << 10) + 8 * pj1);
            LOAD8_SC(qB2, xrow + ((uint64_t)2 << 10) + 8 * pj1); LOAD8_SC(qB3, xrow + ((uint64_t)3 << 10) + 8 * pj1);
            LOAD8_SC(qB4, xrow + ((uint64_t)4 << 10) + 8 * pj1); LOAD8_SC(qB5, xrow + ((uint64_t)5 << 10) + 8 * pj1);
            LOAD8_SC(qB6, xrow + ((uint64_t)6 << 10) + 8 * pj1); LOAD8_SC(qB7, xrow + ((uint64_t)7 << 10) + 8 * pj1);
            asm volatile("s_waitcnt vmcnt(0)" ::: "memory");
            __builtin_amdgcn_sched_barrier(0);
            {
                char* d = gb + (qg)*1040;
                *(uint2*)(d + 0 * 4160 + 8 * pj0) = qA0; *(uint2*)(d + 1 * 4160 + 8 * pj0) = qA1;
                *(uint2*)(d + 2 * 4160 + 8 * pj0) = qA2; *(uint2*)(d + 3 * 4160 + 8 * pj0) = qA3;
                *(uint2*)(d + 4 * 4160 + 8 * pj0) = qA4; *(uint2*)(d + 5 * 4160 + 8 * pj0) = qA5;
                *(uint2*)(d + 6 * 4160 + 8 * pj0) = qA6; *(uint2*)(d + 7 * 4160 + 8 * pj0) = qA7;
                *(uint2*)(d + 0 * 4160 + 8 * pj1) = qB0; *(uint2*)(d + 1 * 4160 + 8 * pj1) = qB1;
                *(uint2*)(d + 2 * 4160 + 8 * pj1) = qB2; *(uint2*)(d + 3 * 4160 + 8 * pj1) = qB3;
                *(uint2*)(d + 4 * 4160 + 8 * pj1) = qB4; *(uint2*)(d + 5 * 4160 + 8 * pj1) = qB5;
                *(uint2*)(d + 6 * 4160 + 8 * pj1) = qB6; *(uint2*)(d + 7 * 4160 + 8 * pj1) = qB7;
            }
            __syncthreads();   // chunk 0 staged; rec waves may start

#pragma unroll 1
            for (int t = 0; t < T_; t += 2) {
                {   // even step: ph==0 -> poll + issue loads for chunk cc=(t>>3)+1
                    const int ph = t & 7;
                    const int cc = (t >> 3) + 1;
                    if (ph == 0 && cc < 64) {
                        poll_one(pfl, (unsigned)(cc * 8 + 8));
                        const uint64_t cb = xrow + ((uint64_t)(cc * 8) << 10);
                        LOAD8_SC(qA0, cb + ((uint64_t)0 << 10) + 8 * pj0); LOAD8_SC(qA1, cb + ((uint64_t)1 << 10) + 8 * pj0);
                        LOAD8_SC(qA2, cb + ((uint64_t)2 << 10) + 8 * pj0); LOAD8_SC(qA3, cb + ((uint64_t)3 << 10) + 8 * pj0);
                        LOAD8_SC(qA4, cb + ((uint64_t)4 << 10) + 8 * pj0); LOAD8_SC(qA5, cb + ((uint64_t)5 << 10) + 8 * pj0);
                        LOAD8_SC(qA6, cb + ((uint64_t)6 << 10) + 8 * pj0); LOAD8_SC(qA7, cb + ((uint64_t)7 << 10) + 8 * pj0);
                        LOAD8_SC(qB0, cb + ((uint64_t)0 << 10) + 8 * pj1); LOAD8_SC(qB1, cb + ((uint64_t)1 << 10) + 8 * pj1);
                        LOAD8_SC(qB2, cb + ((uint64_t)2 << 10) + 8 * pj1); LOAD8_SC(qB3, cb + ((uint64_t)3 << 10) + 8 * pj1);
                        LOAD8_SC(qB4, cb + ((uint64_t)4 << 10) + 8 * pj1); LOAD8_SC(qB5, cb + ((uint64_t)5 << 10) + 8 * pj1);
                        LOAD8_SC(qB6, cb + ((uint64_t)6 << 10) + 8 * pj1); LOAD8_SC(qB7, cb + ((uint64_t)7 << 10) + 8 * pj1);
                    } else if (ph == 2 && cc < 64) {
                        asm volatile("s_waitcnt vmcnt(0)" ::: "memory");
                        __builtin_amdgcn_sched_barrier(0);
                        char* d = gb + ((cc & 1) * 33280) + qg * 1040;
                        *(uint2*)(d + 0 * 4160 + 8 * pj0) = qA0; *(uint2*)(d + 1 * 4160 + 8 * pj0) = qA1;
                        *(uint2*)(d + 2 * 4160 + 8 * pj0) = qA2; *(uint2*)(d + 3 * 4160 + 8 * pj0) = qA3;
                        *(uint2*)(d + 4 * 4160 + 8 * pj0) = qA4; *(uint2*)(d + 5 * 4160 + 8 * pj0) = qA5;
                        *(uint2*)(d + 6 * 4160 + 8 * pj0) = qA6; *(uint2*)(d + 7 * 4160 + 8 * pj0) = qA7;
                        *(uint2*)(d + 0 * 4160 + 8 * pj1) = qB0; *(uint2*)(d + 1 * 4160 + 8 * pj1) = qB1;
                        *(uint2*)(d + 2 * 4160 + 8 * pj1) = qB2; *(uint2*)(d + 3 * 4160 + 8 * pj1) = qB3;
                        *(uint2*)(d + 4 * 4160 + 8 * pj1) = qB4; *(uint2*)(d + 5 * 4160 + 8 * pj1) = qB5;
                        *(uint2*)(d + 6 * 4160 + 8 * pj1) = qB6; *(uint2*)(d + 7 * 4160 + 8 * pj1) = qB7;
                    }
                    lds_barrier();
                }
                lds_barrier();  // odd step: proj idle
            }
        }
    }
}

// ---------- head: out = h2 @ Wc^T + bc (63 cols, f32) ----------
__global__ __launch_bounds__(256, 4)
void head_kernel(const __half* __restrict__ in, const __half* __restrict__ W16,
                 const float* __restrict__ bias, float* __restrict__ outp)
{
    constexpr int KK = 128;
    const int lane = threadIdx.x & 63;
    const int wn = threadIdx.x >> 6;
    const int rowbase = blockIdx.x * 64;
    const int colbase = wn * 16;
    const int l15 = lane & 15, lk = (lane >> 4) * 8;

    float bcol = bias[colbase + l15];
    f32x4 acc[4];
#pragma unroll
    for (int rt = 0; rt < 4; ++rt) acc[rt] = (f32x4){0.f, 0.f, 0.f, 0.f};

#pragma unroll
    for (int kt = 0; kt < 4; ++kt) {
        f16x8 bv = *reinterpret_cast<const f16x8*>(W16 + (size_t)(colbase + l15) * KK + kt * 32 + lk);
#pragma unroll
        for (int rt = 0; rt < 4; ++rt) {
            f16x8 a = *reinterpret_cast<const f16x8*>(in + (size_t)(rowbase + rt * 16 + l15) * KK + kt * 32 + lk);
            acc[rt] = __builtin_amdgcn_mfma_f32_16x16x32_f16(a, bv, acc[rt], 0, 0, 0);
        }
    }
    const int col = colbase + l15;
#pragma unroll
    for (int rt = 0; rt < 4; ++rt)
#pragma unroll
        for (int rr = 0; rr < 4; ++rr) {
            const int row = rowbase + rt * 16 + (lane >> 4) * 4 + rr;
            if (col < 63) outp[(size_t)row * 63 + col] = acc[rt][rr] + bcol;
        }
}

extern "C" void kernel_launch(void* const* d_in, const int* in_sizes, int n_in,
                              void* d_out, int out_size, void* d_ws, size_t ws_size,
                              hipStream_t stream)
{
    const float* x    = (const float*)d_in[0];
    const float* Wih0 = (const float*)d_in[1];
    const float* Whh0 = (const float*)d_in[2];
    const float* bih0 = (const float*)d_in[3];
    const float* bhh0 = (const float*)d_in[4];
    const float* Wih1 = (const float*)d_in[5];
    const float* Whh1 = (const float*)d_in[6];
    const float* bih1 = (const float*)d_in[7];
    const float* bhh1 = (const float*)d_in[8];
    const float* Wl   = (const float*)d_in[9];
    const float* bl   = (const float*)d_in[10];
    const float* Wo   = (const float*)d_in[11];
    const float* bo   = (const float*)d_in[12];
    float* out = (float*)d_out;

    char* ws = (char*)d_ws;
    size_t off = 0;
    auto carve = [&](size_t bytes) { void* p = ws + off; off += (bytes + 255) & ~(size_t)255; return p; };
    __half* xp    = (__half*)carve((size_t)M_ * 512 * 2 + 16384);  // xp1 gate stream
    __half* h2    = (__half*)carve((size_t)M_ * 128 * 2);          // 33.5 MB
    __half* W0b   = (__half*)carve(512 * 32 * 2);
    __half* W1b   = (__half*)carve(512 * 128 * 2);
    __half* Whh0h = (__half*)carve(512 * 128 * 2);
    __half* Whh1h = (__half*)carve(512 * 128 * 2);
    __half* Wc16  = (__half*)carve(64 * 128 * 2);
    float*  b0    = (float*)carve(512 * 4);
    float*  b1    = (float*)carve(512 * 4);
    float*  bc    = (float*)carve(64 * 4);
    unsigned* flags = (unsigned*)carve(512 * 4);

    hipLaunchKernelGGL(convert_kernel, dim3(4), dim3(256), 0, stream,
                       Wih0, bih0, bhh0, Whh0, Wih1, Whh1, bih1, bhh1, Wl, bl, Wo, bo,
                       W0b, W1b, Whh0h, Whh1h, Wc16, b0, b1, bc);

    hipMemsetAsync(flags, 0, 512 * 4, stream);  // flags must start at 0 every replay

    hipLaunchKernelGGL(lstm_fused, dim3(128), dim3(512), 0, stream,
                       x, W0b, Whh0h, W1b, Whh1h, b0, b1, xp, h2, flags);

    hipLaunchKernelGGL(head_kernel, dim3(M_ / 64), dim3(256), 0, stream,
                       h2, Wc16, bc, out);
}